// Round 3
// baseline (365.914 us; speedup 1.0000x reference)
//
#include <hip/hip_runtime.h>
#include <hip/hip_bf16.h>

#define N_NODES 50000
#define E_EDGES 800000
#define D_IN    128
#define HU      256
#define H_HEADS 8
#define U_DIM   32
#define OUT_DIM 64
#define CAP     64

typedef __attribute__((ext_vector_type(8))) short short8v;
typedef __attribute__((ext_vector_type(4))) float f32x4;

__device__ __forceinline__ float bf2f(unsigned short v) {
    return __uint_as_float(((unsigned)v) << 16);
}
__device__ __forceinline__ unsigned short f2b(float f) {  // RNE f32->bf16
    unsigned u = __float_as_uint(f);
    return (unsigned short)((u + 0x7FFFu + ((u >> 16) & 1u)) >> 16);
}

// ---------------- adjacency build (bucket CSR by src) ----------------
__global__ void adj_fill(const int* __restrict__ edges, int* __restrict__ deg,
                         int* __restrict__ adj) {
    int e = blockIdx.x * blockDim.x + threadIdx.x;
    if (e >= E_EDGES) return;
    int2 sd = ((const int2*)edges)[e];
    int slot = atomicAdd(&deg[sd.x], 1);
    if (slot < CAP) adj[(size_t)sd.x * CAP + slot] = sd.y;
}

// ---------------- W -> MFMA B-fragment order (bf16) ----------------
template<int K, int N, bool GAT>
__global__ __launch_bounds__(256) void wfrag_kernel(const float* __restrict__ W,
                                                    unsigned short* __restrict__ Wf) {
    int tid = blockIdx.x * 256 + threadIdx.x;
    if (tid >= K * N) return;
    int j  = tid & 7;
    int l  = (tid >> 3) & 63;
    int fb = tid >> 9;
    int ks = fb % (K / 32);
    int ct = fb / (K / 32);
    int k  = ks * 32 + (l >> 4) * 8 + j;
    int n  = ct * 16 + (l & 15);
    float v = GAT ? W[(size_t)(n >> 5) * (K * 32) + k * 32 + (n & 31)]
                  : W[(size_t)k * N + n];
    Wf[tid] = f2b(v);
}

// ---------------- MFMA GEMM: C[64 x N] = A[64 x K] * W[K x N] ----------------
// MODE 0: f32 out, +bias, relu (pre)   MODE 1: bf16 out (h)   MODE 2: f32 out, +bias (out)
template<int K, int N, int MT, int NT, int MODE>
__global__ __launch_bounds__(256) void mfma_gemm(const float* __restrict__ A,
                                                 const unsigned short* __restrict__ Wf,
                                                 const float* __restrict__ bias,
                                                 void* __restrict__ Cout) {
    constexpr int SK = K + 8;                 // pad: frag reads -> 2-way (free)
    __shared__ __align__(16) unsigned short as[64 * SK];
    int t  = threadIdx.x;
    int n0 = blockIdx.x * 64;

    constexpr int K4 = K / 4;
    const float4* A4 = (const float4*)A;
    for (int i = t; i < 64 * K4; i += 256) {
        int row = i / K4, c4 = i % K4;
        float4 v = make_float4(0.f, 0.f, 0.f, 0.f);
        if (n0 + row < N_NODES) v = A4[(size_t)(n0 + row) * K4 + c4];
        ushort4 pk;
        pk.x = f2b(v.x); pk.y = f2b(v.y); pk.z = f2b(v.z); pk.w = f2b(v.w);
        *(ushort4*)&as[row * SK + c4 * 4] = pk;
    }
    __syncthreads();

    int wid = t >> 6, l = t & 63;
    constexpr int NWN = N / (NT * 16);        // waves along N
    int col0 = (wid % NWN) * (NT * 16);
    int row0 = (wid / NWN) * (MT * 16);

    f32x4 acc[MT][NT];
#pragma unroll
    for (int mt = 0; mt < MT; ++mt)
#pragma unroll
        for (int nt = 0; nt < NT; ++nt)
            acc[mt][nt] = (f32x4){0.f, 0.f, 0.f, 0.f};

    int ar  = l & 15;
    int akb = (l >> 4) * 8;
#pragma unroll
    for (int ks = 0; ks < K / 32; ++ks) {
        short8v a[MT], b[NT];
#pragma unroll
        for (int mt = 0; mt < MT; ++mt)
            a[mt] = *(const short8v*)&as[(row0 + mt * 16 + ar) * SK + ks * 32 + akb];
#pragma unroll
        for (int nt = 0; nt < NT; ++nt)
            b[nt] = *(const short8v*)&Wf[(size_t)(((((col0 >> 4) + nt) * (K / 32)) + ks) * 64 + l) * 8];
#pragma unroll
        for (int mt = 0; mt < MT; ++mt)
#pragma unroll
            for (int nt = 0; nt < NT; ++nt)
                acc[mt][nt] = __builtin_amdgcn_mfma_f32_16x16x32_bf16(a[mt], b[nt], acc[mt][nt], 0, 0, 0);
    }

    int crow = (l >> 4) * 4, ccol = l & 15;
#pragma unroll
    for (int mt = 0; mt < MT; ++mt) {
#pragma unroll
        for (int nt = 0; nt < NT; ++nt) {
            int gc = col0 + nt * 16 + ccol;
#pragma unroll
            for (int r = 0; r < 4; ++r) {
                int gr = n0 + row0 + mt * 16 + crow + r;
                if (gr >= N_NODES) continue;
                float v = acc[mt][nt][r];
                if (MODE == 0) {
                    v += bias[gc];
                    ((float*)Cout)[(size_t)gr * N + gc] = fmaxf(v, 0.f);
                } else if (MODE == 1) {
                    ((unsigned short*)Cout)[(size_t)gr * N + gc] = f2b(v);
                } else {
                    ((float*)Cout)[(size_t)gr * N + gc] = v + bias[gc];
                }
            }
        }
    }
}

// ---------------- s_src/s_dst = per-(node,head) projections of h ----------------
__global__ __launch_bounds__(256) void s_kernel(const unsigned short* __restrict__ h,
                                                const float* __restrict__ al,
                                                float* __restrict__ ssrc,
                                                float* __restrict__ sdst) {
    int n = blockIdx.x, t = threadIdx.x;
    int hd = t >> 5, u = t & 31;
    float hv = bf2f(h[(size_t)n * HU + t]);
    float ps = hv * al[hd * 64 + u];
    float pd = hv * al[hd * 64 + 32 + u];
#pragma unroll
    for (int m = 16; m >= 1; m >>= 1) {
        ps += __shfl_xor(ps, m, 64);
        pd += __shfl_xor(pd, m, 64);
    }
    if (u == 0) {
        ssrc[n * H_HEADS + hd] = ps;
        sdst[n * H_HEADS + hd] = pd;
    }
}

// ---------------- fused attention aggregate + relu + residual (in-place x) ----------------
// 1 wave per node. Score phase: lane t -> (edge t>>3, head t&7), one exp each.
// Agg phase: lane t -> head t>>3, cols (t>>3)*32+(t&7)*4; 8 gathers in flight.
__global__ __launch_bounds__(64) void agg_kernel(const float* __restrict__ x,
                                                 const unsigned short* __restrict__ hb,
                                                 const float* __restrict__ ssrc,
                                                 const float* __restrict__ sdst,
                                                 const int* __restrict__ deg,
                                                 const int* __restrict__ adj,
                                                 float* __restrict__ xo) {
    int n = blockIdx.x, t = threadIdx.x;
    int hd = t >> 3;
    int c = hd * 32 + (t & 7) * 4;
    int dg = deg[n];
    dg = dg > CAP ? CAP : dg;
    const int* arow = adj + (size_t)n * CAP;
    int dl = (t < dg) ? arow[t] : 0;          // lane t holds adj[t]; 0 = safe dummy
    float ss_s = ssrc[n * H_HEADS + (t & 7)]; // score-phase ss for head t&7

    float a0 = 0.f, a1 = 0.f, a2 = 0.f, a3 = 0.f;
    float den_part = 0.f;                     // partial den for head t&7, edges (t>>3)+8k

    for (int base = 0; base < dg; base += 8) {
        // ---- score phase: 8 edges x 8 heads, one exp per lane ----
        int eidx = base + (t >> 3);
        int d_sc = __shfl(dl, eidx);
        float w = 0.f;
        if (eidx < dg) {
            float sc = ss_s + sdst[d_sc * H_HEADS + (t & 7)];
            sc = sc > 0.f ? sc : 0.2f * sc;          // leaky_relu(0.2)
            sc = fminf(fmaxf(sc, -2.f), 2.f);        // clip
            w = __expf(sc);
        }
        den_part += w;
        // ---- aggregation: 8 independent h-row gathers ----
#pragma unroll
        for (int e = 0; e < 8; ++e) {
            if (base + e < dg) {                     // wave-uniform guard
                int d = __shfl(dl, base + e);
                float we = __shfl(w, e * 8 + hd);
                ushort4 hv = *(const ushort4*)(hb + (size_t)d * HU + c);
                a0 += we * bf2f(hv.x);
                a1 += we * bf2f(hv.y);
                a2 += we * bf2f(hv.z);
                a3 += we * bf2f(hv.w);
            }
        }
    }

    // den: reduce over edge-groups (lane bits 3..5), then fetch head hd's den
    float den = den_part;
    den += __shfl_xor(den, 8);
    den += __shfl_xor(den, 16);
    den += __shfl_xor(den, 32);
    den = __shfl(den, hd);                    // lane hd holds head hd (hd<8)

    float inv = dg > 0 ? 1.f / den : 0.f;
    float4 xv = *(const float4*)(x + (size_t)n * HU + c);
    float4 o;
    o.x = fmaxf(a0 * inv, 0.f) + xv.x;
    o.y = fmaxf(a1 * inv, 0.f) + xv.y;
    o.z = fmaxf(a2 * inv, 0.f) + xv.z;
    o.w = fmaxf(a3 * inv, 0.f) + xv.w;
    *(float4*)(xo + (size_t)n * HU + c) = o;
}

extern "C" void kernel_launch(void* const* d_in, const int* in_sizes, int n_in,
                              void* d_out, int out_size, void* d_ws, size_t ws_size,
                              hipStream_t stream) {
    const float* ns   = (const float*)d_in[0];
    const int*   edges= (const int*)d_in[1];
    const float* Wpre = (const float*)d_in[2];
    const float* bpre = (const float*)d_in[3];
    const float* Watt = (const float*)d_in[4];
    const float* aatt = (const float*)d_in[5];
    const float* Wout = (const float*)d_in[6];
    const float* bout = (const float*)d_in[7];
    float* out = (float*)d_out;

    char* p = (char*)d_ws;
    float* xA = (float*)p;                    p += (size_t)N_NODES * HU * 4;
    unsigned short* h = (unsigned short*)p;   p += (size_t)N_NODES * HU * 2;
    float* ssrc = (float*)p;                  p += (size_t)N_NODES * H_HEADS * 4;
    float* sdst = (float*)p;                  p += (size_t)N_NODES * H_HEADS * 4;
    int* deg = (int*)p;                       p += (size_t)N_NODES * 4;
    int* adj = (int*)p;                       p += (size_t)N_NODES * CAP * 4;
    unsigned short* wf_pre  = (unsigned short*)p; p += (size_t)D_IN * HU * 2;
    unsigned short* wf_att0 = (unsigned short*)p; p += (size_t)HU * HU * 2;
    unsigned short* wf_att1 = (unsigned short*)p; p += (size_t)HU * HU * 2;
    unsigned short* wf_out  = (unsigned short*)p; p += (size_t)HU * OUT_DIM * 2;

    wfrag_kernel<D_IN, HU, false><<<(D_IN * HU) / 256, 256, 0, stream>>>(Wpre, wf_pre);
    wfrag_kernel<HU, HU, true><<<(HU * HU) / 256, 256, 0, stream>>>(Watt, wf_att0);
    wfrag_kernel<HU, HU, true><<<(HU * HU) / 256, 256, 0, stream>>>(Watt + 65536, wf_att1);
    wfrag_kernel<HU, OUT_DIM, false><<<(HU * OUT_DIM) / 256, 256, 0, stream>>>(Wout, wf_out);

    hipMemsetAsync(deg, 0, (size_t)N_NODES * 4, stream);
    adj_fill<<<(E_EDGES + 255) / 256, 256, 0, stream>>>(edges, deg, adj);

    const int GB = (N_NODES + 63) / 64;   // 782
    mfma_gemm<D_IN, HU, 4, 4, 0><<<GB, 256, 0, stream>>>(ns, wf_pre, bpre, xA);

    unsigned short* wf_att[2] = {wf_att0, wf_att1};
    for (int l = 0; l < 2; ++l) {
        mfma_gemm<HU, HU, 4, 4, 1><<<GB, 256, 0, stream>>>(xA, wf_att[l], nullptr, h);
        s_kernel<<<N_NODES, 256, 0, stream>>>(h, aatt + (size_t)l * 512, ssrc, sdst);
        agg_kernel<<<N_NODES, 64, 0, stream>>>(xA, h, ssrc, sdst, deg, adj, xA);
    }

    mfma_gemm<HU, OUT_DIM, 1, 4, 2><<<GB, 256, 0, stream>>>(xA, wf_out, bout, out);
}

// Round 4
// 301.447 us; speedup vs baseline: 1.2139x; 1.2139x over previous
//
#include <hip/hip_runtime.h>
#include <hip/hip_bf16.h>

#define N_NODES 50000
#define E_EDGES 800000
#define D_IN    128
#define HU      256
#define H_HEADS 8
#define U_DIM   32
#define OUT_DIM 64
#define CAP     64

typedef __attribute__((ext_vector_type(8))) short short8v;
typedef __attribute__((ext_vector_type(4))) float f32x4;
typedef unsigned short u16;
typedef __attribute__((ext_vector_type(4))) unsigned short u16x4;
typedef __attribute__((ext_vector_type(8))) unsigned short u16x8;

__device__ __forceinline__ float bf2f(u16 v) {
    return __uint_as_float(((unsigned)v) << 16);
}
__device__ __forceinline__ u16 f2b(float f) {  // RNE f32->bf16
    unsigned u = __float_as_uint(f);
    return (u16)((u + 0x7FFFu + ((u >> 16) & 1u)) >> 16);
}

// ---------------- adjacency build (bucket CSR by src, u16 dst) ----------------
__global__ void adj_fill(const int* __restrict__ edges, int* __restrict__ deg,
                         u16* __restrict__ adj) {
    int e = blockIdx.x * blockDim.x + threadIdx.x;
    if (e >= E_EDGES) return;
    int2 sd = ((const int2*)edges)[e];
    int slot = atomicAdd(&deg[sd.x], 1);
    if (slot < CAP) adj[(size_t)sd.x * CAP + slot] = (u16)sd.y;
}

// ---------------- W -> MFMA B-fragment order (bf16) ----------------
// Wf[(((ct*(K/32)+ks)*64 + l)*8 + j] = W[k][n], k=ks*32+(l>>4)*8+j, n=ct*16+(l&15)
template<int K, int N, bool GAT>
__device__ __forceinline__ void wfrag_one(const float* __restrict__ W,
                                          u16* __restrict__ Wf, int tid) {
    int j  = tid & 7;
    int l  = (tid >> 3) & 63;
    int fb = tid >> 9;
    int ks = fb % (K / 32);
    int ct = fb / (K / 32);
    int k  = ks * 32 + (l >> 4) * 8 + j;
    int n  = ct * 16 + (l & 15);
    float v = GAT ? W[(size_t)(n >> 5) * (K * 32) + k * 32 + (n & 31)]
                  : W[(size_t)k * N + n];
    Wf[tid] = f2b(v);
}

// Wa[k, n] : n<8 -> sum_u Watt[n][k][u]*a[n][u] (src); n>=8 -> dst half
__device__ __forceinline__ void wa_one(const float* __restrict__ Watt,
                                       const float* __restrict__ al,
                                       u16* __restrict__ Wfs, int tid) {
    int j  = tid & 7;
    int l  = (tid >> 3) & 63;
    int ks = tid >> 9;
    int k  = ks * 32 + (l >> 4) * 8 + j;
    int n  = l & 15;
    int hd = n & 7;
    int off = (n < 8) ? 0 : 32;
    float s = 0.f;
#pragma unroll
    for (int u = 0; u < 32; ++u)
        s += Watt[(size_t)hd * 8192 + k * 32 + u] * al[hd * 64 + off + u];
    Wfs[tid] = f2b(s);
}

__global__ __launch_bounds__(256) void wfrag_all(const float* __restrict__ Wpre,
                                                 const float* __restrict__ Watt,
                                                 const float* __restrict__ aatt,
                                                 const float* __restrict__ Wout,
                                                 u16* __restrict__ wf_pre,
                                                 u16* __restrict__ wf_a0,
                                                 u16* __restrict__ wf_a1,
                                                 u16* __restrict__ wf_out,
                                                 u16* __restrict__ wfs0,
                                                 u16* __restrict__ wfs1) {
    int tid = blockIdx.x * 256 + threadIdx.x;
    if (tid < 32768)        wfrag_one<D_IN, HU, false>(Wpre, wf_pre, tid);
    else if (tid < 98304)   wfrag_one<HU, HU, true>(Watt, wf_a0, tid - 32768);
    else if (tid < 163840)  wfrag_one<HU, HU, true>(Watt + 65536, wf_a1, tid - 98304);
    else if (tid < 180224)  wfrag_one<HU, OUT_DIM, false>(Wout, wf_out, tid - 163840);
    else if (tid < 184320)  wa_one(Watt, aatt, wfs0, tid - 180224);
    else if (tid < 188416)  wa_one(Watt + 65536, aatt + 512, wfs1, tid - 184320);
}

// ---------------- MFMA GEMM: C[64 x N] = A[64 x K] * W[K x N] ----------------
// MODE 0: bf16 out, +bias, relu (pre)  MODE 1: bf16 out + fused s (h)  MODE 2: f32 out, +bias
template<int K, int N, int MT, int NT, int MODE, bool ABF16>
__global__ __launch_bounds__(256) void mfma_gemm(const void* __restrict__ Ain,
                                                 const u16* __restrict__ Wf,
                                                 const float* __restrict__ bias,
                                                 void* __restrict__ Cout,
                                                 const u16* __restrict__ wfs,
                                                 u16* __restrict__ sb,
                                                 u16* __restrict__ db) {
    constexpr int SK = K + 8;
    __shared__ __align__(16) u16 as[64 * SK];
    int t  = threadIdx.x;
    int n0 = blockIdx.x * 64;

    if (ABF16) {
        constexpr int K8 = K / 8;
        const u16x8* A8 = (const u16x8*)Ain;
        for (int i = t; i < 64 * K8; i += 256) {
            int row = i / K8, c8 = i % K8;
            u16x8 v = {0, 0, 0, 0, 0, 0, 0, 0};
            if (n0 + row < N_NODES)
                v = __builtin_nontemporal_load(&A8[(size_t)(n0 + row) * K8 + c8]);
            *(u16x8*)&as[row * SK + c8 * 8] = v;
        }
    } else {
        constexpr int K4 = K / 4;
        const f32x4* A4 = (const f32x4*)Ain;
        for (int i = t; i < 64 * K4; i += 256) {
            int row = i / K4, c4 = i % K4;
            f32x4 v = {0.f, 0.f, 0.f, 0.f};
            if (n0 + row < N_NODES)
                v = __builtin_nontemporal_load(&A4[(size_t)(n0 + row) * K4 + c4]);
            u16x4 pk;
            pk.x = f2b(v.x); pk.y = f2b(v.y); pk.z = f2b(v.z); pk.w = f2b(v.w);
            *(u16x4*)&as[row * SK + c4 * 4] = pk;
        }
    }
    __syncthreads();

    int wid = t >> 6, l = t & 63;
    constexpr int NWN = N / (NT * 16);
    int col0 = (wid % NWN) * (NT * 16);
    int row0 = (wid / NWN) * (MT * 16);

    f32x4 acc[MT][NT];
#pragma unroll
    for (int mt = 0; mt < MT; ++mt)
#pragma unroll
        for (int nt = 0; nt < NT; ++nt)
            acc[mt][nt] = (f32x4){0.f, 0.f, 0.f, 0.f};
    f32x4 accs[MT];
#pragma unroll
    for (int mt = 0; mt < MT; ++mt) accs[mt] = (f32x4){0.f, 0.f, 0.f, 0.f};

    int ar  = l & 15;
    int akb = (l >> 4) * 8;
#pragma unroll
    for (int ks = 0; ks < K / 32; ++ks) {
        short8v a[MT], b[NT];
#pragma unroll
        for (int mt = 0; mt < MT; ++mt)
            a[mt] = *(const short8v*)&as[(row0 + mt * 16 + ar) * SK + ks * 32 + akb];
#pragma unroll
        for (int nt = 0; nt < NT; ++nt)
            b[nt] = *(const short8v*)&Wf[(size_t)(((((col0 >> 4) + nt) * (K / 32)) + ks) * 64 + l) * 8];
        if (MODE == 1) {
            if (wid == 0) {
                short8v bs = *(const short8v*)&wfs[(size_t)(ks * 64 + l) * 8];
#pragma unroll
                for (int mt = 0; mt < MT; ++mt)
                    accs[mt] = __builtin_amdgcn_mfma_f32_16x16x32_bf16(a[mt], bs, accs[mt], 0, 0, 0);
            }
        }
#pragma unroll
        for (int mt = 0; mt < MT; ++mt)
#pragma unroll
            for (int nt = 0; nt < NT; ++nt)
                acc[mt][nt] = __builtin_amdgcn_mfma_f32_16x16x32_bf16(a[mt], b[nt], acc[mt][nt], 0, 0, 0);
    }

    int crow = (l >> 4) * 4, ccol = l & 15;
#pragma unroll
    for (int mt = 0; mt < MT; ++mt) {
#pragma unroll
        for (int nt = 0; nt < NT; ++nt) {
            int gc = col0 + nt * 16 + ccol;
#pragma unroll
            for (int r = 0; r < 4; ++r) {
                int gr = n0 + row0 + mt * 16 + crow + r;
                if (gr >= N_NODES) continue;
                float v = acc[mt][nt][r];
                if (MODE == 0) {
                    v += bias[gc];
                    ((u16*)Cout)[(size_t)gr * N + gc] = f2b(fmaxf(v, 0.f));
                } else if (MODE == 1) {
                    ((u16*)Cout)[(size_t)gr * N + gc] = f2b(v);
                } else {
                    ((float*)Cout)[(size_t)gr * N + gc] = v + bias[gc];
                }
            }
        }
    }
    if (MODE == 1) {
        if (wid == 0) {   // s columns: ccol<8 -> ssrc head ccol, else sdst head ccol-8
#pragma unroll
            for (int mt = 0; mt < MT; ++mt) {
#pragma unroll
                for (int r = 0; r < 4; ++r) {
                    int gr = n0 + mt * 16 + crow + r;
                    if (gr >= N_NODES) continue;
                    float v = accs[mt][r];
                    if (ccol < 8) sb[(size_t)gr * 8 + ccol] = f2b(v);
                    else          db[(size_t)gr * 8 + ccol - 8] = f2b(v);
                }
            }
        }
    }
}

// ---------------- fused attention aggregate + relu + residual (in-place bf16 x) ----------------
__global__ __launch_bounds__(64) void agg_kernel(const u16* __restrict__ hb,
                                                 const u16* __restrict__ ssrcb,
                                                 const u16* __restrict__ sdstb,
                                                 const int* __restrict__ deg,
                                                 const u16* __restrict__ adj,
                                                 u16* __restrict__ x) {
    int n = blockIdx.x, t = threadIdx.x;
    int hd = t >> 3;
    int c = hd * 32 + (t & 7) * 4;
    int dg = deg[n];
    dg = dg > CAP ? CAP : dg;
    int dl = (t < dg) ? (int)__builtin_nontemporal_load(&adj[(size_t)n * CAP + t]) : 0;
    float ss_s = bf2f(ssrcb[(size_t)n * 8 + (t & 7)]);

    float a0 = 0.f, a1 = 0.f, a2 = 0.f, a3 = 0.f;
    float den_part = 0.f;

    for (int base = 0; base < dg; base += 8) {
        int eidx = base + (t >> 3);
        int d_sc = __shfl(dl, eidx);
        float w = 0.f;
        if (eidx < dg) {
            float sc = ss_s + bf2f(sdstb[(size_t)d_sc * 8 + (t & 7)]);
            sc = sc > 0.f ? sc : 0.2f * sc;          // leaky_relu(0.2)
            sc = fminf(fmaxf(sc, -2.f), 2.f);        // clip
            w = __expf(sc);
        }
        den_part += w;
#pragma unroll
        for (int e = 0; e < 8; ++e) {
            if (base + e < dg) {
                int d = __shfl(dl, base + e);
                float we = __shfl(w, e * 8 + hd);
                u16x4 hv = *(const u16x4*)(hb + (size_t)d * HU + c);
                a0 += we * bf2f(hv.x);
                a1 += we * bf2f(hv.y);
                a2 += we * bf2f(hv.z);
                a3 += we * bf2f(hv.w);
            }
        }
    }

    float den = den_part;
    den += __shfl_xor(den, 8);
    den += __shfl_xor(den, 16);
    den += __shfl_xor(den, 32);
    den = __shfl(den, hd);

    float inv = dg > 0 ? 1.f / den : 0.f;
    u16x4 xv = __builtin_nontemporal_load((const u16x4*)(x + (size_t)n * HU + c));
    u16x4 o;
    o.x = f2b(fmaxf(a0 * inv, 0.f) + bf2f(xv.x));
    o.y = f2b(fmaxf(a1 * inv, 0.f) + bf2f(xv.y));
    o.z = f2b(fmaxf(a2 * inv, 0.f) + bf2f(xv.z));
    o.w = f2b(fmaxf(a3 * inv, 0.f) + bf2f(xv.w));
    __builtin_nontemporal_store(o, (u16x4*)(x + (size_t)n * HU + c));
}

extern "C" void kernel_launch(void* const* d_in, const int* in_sizes, int n_in,
                              void* d_out, int out_size, void* d_ws, size_t ws_size,
                              hipStream_t stream) {
    const float* ns   = (const float*)d_in[0];
    const int*   edges= (const int*)d_in[1];
    const float* Wpre = (const float*)d_in[2];
    const float* bpre = (const float*)d_in[3];
    const float* Watt = (const float*)d_in[4];
    const float* aatt = (const float*)d_in[5];
    const float* Wout = (const float*)d_in[6];
    const float* bout = (const float*)d_in[7];
    float* out = (float*)d_out;

    char* p = (char*)d_ws;
    u16* xA = (u16*)p;               p += (size_t)N_NODES * HU * 2;
    u16* h = (u16*)p;                p += (size_t)N_NODES * HU * 2;
    u16* ssrcb = (u16*)p;            p += (size_t)N_NODES * H_HEADS * 2;
    u16* sdstb = (u16*)p;            p += (size_t)N_NODES * H_HEADS * 2;
    int* deg = (int*)p;              p += (size_t)N_NODES * 4;
    u16* adj = (u16*)p;              p += (size_t)N_NODES * CAP * 2;
    u16* wf_pre  = (u16*)p;          p += (size_t)D_IN * HU * 2;
    u16* wf_att0 = (u16*)p;          p += (size_t)HU * HU * 2;
    u16* wf_att1 = (u16*)p;          p += (size_t)HU * HU * 2;
    u16* wf_out  = (u16*)p;          p += (size_t)HU * OUT_DIM * 2;
    u16* wfs0 = (u16*)p;             p += (size_t)4096 * 2;
    u16* wfs1 = (u16*)p;             p += (size_t)4096 * 2;

    wfrag_all<<<736, 256, 0, stream>>>(Wpre, Watt, aatt, Wout,
                                       wf_pre, wf_att0, wf_att1, wf_out, wfs0, wfs1);

    hipMemsetAsync(deg, 0, (size_t)N_NODES * 4, stream);
    adj_fill<<<(E_EDGES + 255) / 256, 256, 0, stream>>>(edges, deg, adj);

    const int GB = (N_NODES + 63) / 64;   // 782
    mfma_gemm<D_IN, HU, 4, 4, 0, false><<<GB, 256, 0, stream>>>(
        ns, wf_pre, bpre, xA, nullptr, nullptr, nullptr);

    u16* wf_att[2] = {wf_att0, wf_att1};
    u16* wfs[2] = {wfs0, wfs1};
    for (int l = 0; l < 2; ++l) {
        mfma_gemm<HU, HU, 4, 4, 1, true><<<GB, 256, 0, stream>>>(
            xA, wf_att[l], nullptr, h, wfs[l], ssrcb, sdstb);
        agg_kernel<<<N_NODES, 64, 0, stream>>>(h, ssrcb, sdstb, deg, adj, xA);
    }

    mfma_gemm<HU, OUT_DIM, 1, 4, 2, true><<<GB, 256, 0, stream>>>(
        xA, wf_out, bout, out, nullptr, nullptr, nullptr);
}